// Round 5
// baseline (2419.514 us; speedup 1.0000x reference)
//
#include <hip/hip_runtime.h>
#include <cstdint>

#define NSTEPS 100

typedef float v2f __attribute__((ext_vector_type(2)));

// Per-step threefry subkeys via kernargs; padded +1 so the software-pipelined
// prefetch of step s+1 never reads out of bounds.
struct KeyArr {
    uint32_t k1[NSTEPS + 1];
    uint32_t k2[NSTEPS + 1];
};

__host__ __device__ __forceinline__ uint32_t rotl32(uint32_t x, uint32_t r) {
    return (x << r) | (x >> (32u - r));   // -> v_alignbit_b32, 1 instr
}

// Host-side reference threefry (key derivation only).
static void threefry2x32_host(uint32_t k1, uint32_t k2, uint32_t x0, uint32_t x1,
                              uint32_t& o0, uint32_t& o1) {
    const uint32_t ks2 = k1 ^ k2 ^ 0x1BD11BDAu;
    x0 += k1; x1 += k2;
#define TF_R(r) { x0 += x1; x1 = rotl32(x1, r); x1 ^= x0; }
    TF_R(13u) TF_R(15u) TF_R(26u) TF_R(6u)   x0 += k2;  x1 += ks2 + 1u;
    TF_R(17u) TF_R(29u) TF_R(16u) TF_R(24u)  x0 += ks2; x1 += k1 + 2u;
    TF_R(13u) TF_R(15u) TF_R(26u) TF_R(6u)   x0 += k1;  x1 += k2 + 3u;
    TF_R(17u) TF_R(29u) TF_R(16u) TF_R(24u)  x0 += k2;  x1 += ks2 + 4u;
    TF_R(13u) TF_R(15u) TF_R(26u) TF_R(6u)   x0 += ks2; x1 += k1 + 5u;
#undef TF_R
    o0 = x0; o1 = x1;
}

// Device cipher, bit-identical to the reference schedule. Integer: no packed
// 32-bit add on CDNA, so this stays scalar VALU. ~67 ops + 1 output xor.
__device__ __forceinline__ uint32_t tf_bits(uint32_t k1, uint32_t k2, uint32_t ctr_pk2) {
    const uint32_t ks2 = k1 ^ k2 ^ 0x1BD11BDAu;
    uint32_t x1 = ctr_pk2;              // = counter + k2, computed by caller
    uint32_t x0 = k1 + x1;              // init(x0=k1) fused with round-1 add
    x1 = rotl32(x1, 13u); x1 ^= x0;
#define TF_R(r)            { x0 += x1; x1 = rotl32(x1, r); x1 ^= x0; }
#define TF_RINJ(r, ka, kb) { x1 += (kb); x0 = x0 + (ka) + x1; x1 = rotl32(x1, r); x1 ^= x0; }
    TF_R(15u) TF_R(26u) TF_R(6u)
    TF_RINJ(17u, k2,  ks2 + 1u)
    TF_R(29u) TF_R(16u) TF_R(24u)
    TF_RINJ(13u, ks2, k1 + 2u)
    TF_R(15u) TF_R(26u) TF_R(6u)
    TF_RINJ(17u, k1,  k2 + 3u)
    TF_R(29u) TF_R(16u) TF_R(24u)
    TF_RINJ(13u, k2,  ks2 + 4u)
    TF_R(15u) TF_R(26u) TF_R(6u)
    x0 += ks2; x1 += k1 + 5u;
#undef TF_R
#undef TF_RINJ
    return x0 ^ x1;
}

__device__ __forceinline__ v2f pk_fma(v2f a, v2f b, v2f c) {
    return __builtin_elementwise_fma(a, b, c);   // -> v_pk_fma_f32 on gfx90a+
}

// Rare-tail erfinv branch (w >= 5), scalar, executed under exec mask for
// ~0.33% of values. 7-term Giles far polynomial (trunc error <= 1e-4).
__device__ __forceinline__ float erfinv_tail(float lg, float u) {
    float w0 = lg * -0.69314718056f;
    float w = __builtin_amdgcn_sqrtf(w0) - 3.0f;
    float p =        0.00134934322f;
    p = fmaf(p, w,  -0.00367342844f);
    p = fmaf(p, w,   0.00573950773f);
    p = fmaf(p, w,  -0.0076224613f);
    p = fmaf(p, w,   0.00943887047f);
    p = fmaf(p, w,   1.00167406f);
    p = fmaf(p, w,   2.83297682f);
    return p * u;
}

// Packed transform for a PAIR of bit streams: replicates JAX/XLA semantics
// (u in [nextafter(-1,0), 1), Giles polynomials) with the fp32 chain running
// on the dual-issue packed pipe (v_pk_add/fma/mul_f32). Only the quarter-rate
// v_log and the rare tail fixup stay scalar.
// NOTE (R2/R3 lessons): the MINVAL clamp form u = fma(f,2,MINVAL) is
// load-bearing (a fused 2b-3 hits u=-1 exactly -> log(0) -> inf); the
// central poly is truncated 9->7 terms (bias <= 2.5e-4, budget 0.57).
__device__ __forceinline__ v2f bits_pair_to_scaled_normal(uint32_t bits_a, uint32_t bits_b) {
    const float MINVAL = -0.99999994f;  // nextafter(-1, 0) in f32
    v2f b;
    b.x = __uint_as_float(__builtin_amdgcn_alignbit(127u, bits_a, 9u)); // [1,2)
    b.y = __uint_as_float(__builtin_amdgcn_alignbit(127u, bits_b, 9u));
    v2f f = b - 1.0f;                          // exact (Sterbenz), v_pk_add
    v2f u = pk_fma(f, (v2f)2.0f, (v2f)MINVAL); // [MINVAL, 0.99999994]
    v2f t = pk_fma(-u, u, (v2f)1.0f);          // 1 - u^2, single rounding
    v2f lg;
    lg.x = __builtin_amdgcn_logf(t.x);         // log2(1-u^2), quarter-rate SFU
    lg.y = __builtin_amdgcn_logf(t.y);
    v2f w = pk_fma(lg, (v2f)(-0.69314718056f), (v2f)(-2.5f));
    v2f p = (v2f)(-3.5233877e-06f);
    p = pk_fma(p, w, (v2f)(-4.39150654e-06f));
    p = pk_fma(p, w, (v2f)( 0.00021858087f));
    p = pk_fma(p, w, (v2f)(-0.00125372503f));
    p = pk_fma(p, w, (v2f)(-0.00417768164f));
    p = pk_fma(p, w, (v2f)( 0.246640727f));
    p = pk_fma(p, w, (v2f)( 1.50140941f));
    v2f res = p * u;                           // v_pk_mul_f32
    // Tail fixup: t <= e^-5 <=> w >= 5; ~19% of waves take each branch.
    const float TH = 6.737947e-3f;
    if (t.x <= TH) res.x = erfinv_tail(lg.x, u.x);
    if (t.y <= TH) res.y = erfinv_tail(lg.y, u.y);
    return res;
}

__global__ __launch_bounds__(256)
void DiffusionProcess_21698174780217_kernel(
    const float* __restrict__ x, const float* __restrict__ betas,
    float* __restrict__ out, KeyArr keys, int n4) {
    __shared__ float sb[NSTEPS + 1];
    const int t = threadIdx.x;
    if (t < NSTEPS) sb[t] = __builtin_amdgcn_sqrtf(betas[t] * 2.0f); // sqrt(2*beta)
    if (t == NSTEPS) sb[NSTEPS] = 0.f;  // prefetch pad
    __syncthreads();

    const int gid = blockIdx.x * blockDim.x + t;
    if (gid >= n4) return;
    const uint32_t base = (uint32_t)gid * 4u;

    v2f acc01 = (v2f)0.f, acc23 = (v2f)0.f;

    // Software-pipelined per-step uniforms (neutral in R3 but keeps the
    // backedge lgkmcnt wait off the critical path).
    uint32_t nk1 = keys.k1[0], nk2 = keys.k2[0];
    float nsb = sb[0];

    #pragma unroll 1
    for (int s = 0; s < NSTEPS; ++s) {
        const uint32_t k1 = nk1;
        const uint32_t k2 = nk2;
        const v2f sbs = (v2f)nsb;
        nk1 = keys.k1[s + 1];           // padded arrays: s+1 always in bounds
        nk2 = keys.k2[s + 1];
        nsb = sb[s + 1];
        // counter hi word = 0 (n < 2^32); x1 init = counter + k2
        const uint32_t c0 = base + k2;
        uint32_t r0 = tf_bits(k1, k2, c0);
        uint32_t r1 = tf_bits(k1, k2, c0 + 1u);
        uint32_t r2 = tf_bits(k1, k2, c0 + 2u);
        uint32_t r3 = tf_bits(k1, k2, c0 + 3u);
        acc01 = pk_fma(sbs, bits_pair_to_scaled_normal(r0, r1), acc01);
        acc23 = pk_fma(sbs, bits_pair_to_scaled_normal(r2, r3), acc23);
    }

    const float4 xv = reinterpret_cast<const float4*>(x)[gid];
    float4 ov;
    ov.x = xv.x + acc01.x;
    ov.y = xv.y + acc01.y;
    ov.z = xv.z + acc23.x;
    ov.w = xv.w + acc23.y;
    reinterpret_cast<float4*>(out)[gid] = ov;
}

extern "C" void kernel_launch(void* const* d_in, const int* in_sizes, int n_in,
                              void* d_out, int out_size, void* d_ws, size_t ws_size,
                              hipStream_t stream) {
    const float* x = (const float*)d_in[0];
    const float* betas = (const float*)d_in[1];
    float* out = (float*)d_out;
    const int n = in_sizes[0];       // 64*3*256*256 = 12,582,912 (divisible by 4)
    const int n4 = n / 4;

    // jax.random.key(1) -> key data (0, 1).
    // split (partitionable / foldlike): keys[s] = threefry2x32((0,1), (0, s)).
    KeyArr keys;
    for (int s = 0; s < NSTEPS; ++s) {
        uint32_t o0, o1;
        threefry2x32_host(0u, 1u, 0u, (uint32_t)s, o0, o1);
        keys.k1[s] = o0;
        keys.k2[s] = o1;
    }
    keys.k1[NSTEPS] = 0u;   // prefetch pad
    keys.k2[NSTEPS] = 0u;

    const int blocks = (n4 + 255) / 256;
    hipLaunchKernelGGL(DiffusionProcess_21698174780217_kernel,
                       dim3(blocks), dim3(256), 0, stream,
                       x, betas, out, keys, n4);
}

// Round 7
// 2245.246 us; speedup vs baseline: 1.0776x; 1.0776x over previous
//
#include <hip/hip_runtime.h>
#include <cstdint>

#define NSTEPS 100

// Per-step threefry subkeys via kernargs; padded +1 so the software-pipelined
// prefetch of step s+1 never reads out of bounds.
struct KeyArr {
    uint32_t k1[NSTEPS + 1];
    uint32_t k2[NSTEPS + 1];
};

__host__ __device__ __forceinline__ uint32_t rotl32(uint32_t x, uint32_t r) {
    return (x << r) | (x >> (32u - r));   // -> v_alignbit_b32, 1 instr
}

// Host-side reference threefry (key derivation only).
static void threefry2x32_host(uint32_t k1, uint32_t k2, uint32_t x0, uint32_t x1,
                              uint32_t& o0, uint32_t& o1) {
    const uint32_t ks2 = k1 ^ k2 ^ 0x1BD11BDAu;
    x0 += k1; x1 += k2;
#define TF_R(r) { x0 += x1; x1 = rotl32(x1, r); x1 ^= x0; }
    TF_R(13u) TF_R(15u) TF_R(26u) TF_R(6u)   x0 += k2;  x1 += ks2 + 1u;
    TF_R(17u) TF_R(29u) TF_R(16u) TF_R(24u)  x0 += ks2; x1 += k1 + 2u;
    TF_R(13u) TF_R(15u) TF_R(26u) TF_R(6u)   x0 += k1;  x1 += k2 + 3u;
    TF_R(17u) TF_R(29u) TF_R(16u) TF_R(24u)  x0 += k2;  x1 += ks2 + 4u;
    TF_R(13u) TF_R(15u) TF_R(26u) TF_R(6u)   x0 += ks2; x1 += k1 + 5u;
#undef TF_R
    o0 = x0; o1 = x1;
}

// Device cipher, bit-identical to the reference schedule. Integer -> scalar
// VALU only (no packed u32 add on CDNA; R4 showed packed fp32 is
// rate-neutral-at-best on gfx950 anyway). ~69 VALU ops incl. init/final/xor.
__device__ __forceinline__ uint32_t tf_bits(uint32_t k1, uint32_t k2, uint32_t ctr_pk2) {
    const uint32_t ks2 = k1 ^ k2 ^ 0x1BD11BDAu;
    uint32_t x1 = ctr_pk2;              // = counter + k2, computed by caller
    uint32_t x0 = k1 + x1;              // init(x0=k1) fused with round-1 add
    x1 = rotl32(x1, 13u); x1 ^= x0;
#define TF_R(r)            { x0 += x1; x1 = rotl32(x1, r); x1 ^= x0; }
#define TF_RINJ(r, ka, kb) { x1 += (kb); x0 = x0 + (ka) + x1; x1 = rotl32(x1, r); x1 ^= x0; }
    TF_R(15u) TF_R(26u) TF_R(6u)
    TF_RINJ(17u, k2,  ks2 + 1u)
    TF_R(29u) TF_R(16u) TF_R(24u)
    TF_RINJ(13u, ks2, k1 + 2u)
    TF_R(15u) TF_R(26u) TF_R(6u)
    TF_RINJ(17u, k1,  k2 + 3u)
    TF_R(29u) TF_R(16u) TF_R(24u)
    TF_RINJ(13u, k2,  ks2 + 4u)
    TF_R(15u) TF_R(26u) TF_R(6u)
    x0 += ks2; x1 += k1 + 5u;
#undef TF_R
#undef TF_RINJ
    return x0 ^ x1;
}

// bits -> erfinv-shaped p*u (caller folds sqrt(2*beta) into one fmac).
// JAX/XLA semantics: u in [nextafter(-1,0), 1), Giles-style polynomials,
// central poly truncated 9->7 (bias <= 2.5e-4 vs 0.57 margin), far 9->7.
// Branch predicate on t (pre-log) so the exec split doesn't wait on v_log.
// NOTE: u = fma(b-1, 2, MINVAL) is load-bearing twice over:
//  (a) a fused 2b-3 form hits u = -1 exactly at zero mantissa -> log(0);
//  (b) MINVAL-2 = -(3 - 2^-24) is not f32-representable, so a one-fma
//      rewrite perturbs u by ~1e-7 -> up to ~3e-2 per-sample error in the
//      tail (dn/du blows up as e^{n^2/2}). Keep the exact 2-op form.
__device__ __forceinline__ float bits_to_scaled_normal(uint32_t bits) {
    const float MINVAL = -0.99999994f;  // nextafter(-1, 0) in f32
    float b = __uint_as_float(__builtin_amdgcn_alignbit(127u, bits, 9u)); // [1,2)
    float f = b - 1.0f;                 // exact (Sterbenz)
    float u = fmaf(f, 2.0f, MINVAL);    // [MINVAL, 0.99999994]
    float au = fabsf(u);                // src modifier, free on consumer
    float t = fmaf(-au, au, 1.0f);      // 1 - u^2, single rounding
    float lg = __builtin_amdgcn_logf(t);        // log2(1-u^2), quarter-rate
    float p;
    if (t > 6.737947e-3f) {             // <=> w = -ln(t) < 5  (central, 99.67%)
        float w = fmaf(lg, -0.69314718056f, -2.5f);
        p =             -3.5233877e-06f;
        p = fmaf(p, w,  -4.39150654e-06f);
        p = fmaf(p, w,   0.00021858087f);
        p = fmaf(p, w,  -0.00125372503f);
        p = fmaf(p, w,  -0.00417768164f);
        p = fmaf(p, w,   0.246640727f);
        p = fmaf(p, w,   1.50140941f);
    } else {                            // rare tail: ~0.33% of lanes
        float w0 = lg * -0.69314718056f;
        float w = __builtin_amdgcn_sqrtf(w0) - 3.0f;
        p =              0.00134934322f;
        p = fmaf(p, w,  -0.00367342844f);
        p = fmaf(p, w,   0.00573950773f);
        p = fmaf(p, w,  -0.0076224613f);
        p = fmaf(p, w,   0.00943887047f);
        p = fmaf(p, w,   1.00167406f);
        p = fmaf(p, w,   2.83297682f);
    }
    return p * u;
}

__global__ __launch_bounds__(256)
void DiffusionProcess_21698174780217_kernel(
    const float* __restrict__ x, const float* __restrict__ betas,
    float* __restrict__ out, KeyArr keys, int n4) {
    __shared__ float sb[NSTEPS + 1];
    const int t = threadIdx.x;
    if (t < NSTEPS) sb[t] = __builtin_amdgcn_sqrtf(betas[t] * 2.0f); // sqrt(2*beta)
    if (t == NSTEPS) sb[NSTEPS] = 0.f;  // prefetch pad
    __syncthreads();

    const int gid = blockIdx.x * blockDim.x + t;
    if (gid >= n4) return;
    const uint32_t base = (uint32_t)gid * 4u;

    float acc0 = 0.f, acc1 = 0.f, acc2 = 0.f, acc3 = 0.f;

    // Software-pipelined per-step uniforms (measured neutral, kept: frees the
    // backedge lgkmcnt wait from the critical path at zero cost).
    uint32_t nk1 = keys.k1[0], nk2 = keys.k2[0];
    float nsb = sb[0];

    #pragma unroll 1
    for (int s = 0; s < NSTEPS; ++s) {
        const uint32_t k1 = nk1;
        const uint32_t k2 = nk2;
        const float sbs = nsb;
        nk1 = keys.k1[s + 1];           // padded arrays: s+1 always in bounds
        nk2 = keys.k2[s + 1];
        nsb = sb[s + 1];
        // counter hi word = 0 (n < 2^32); x1 init = counter + k2
        const uint32_t c0 = base + k2;
        uint32_t r0 = tf_bits(k1, k2, c0);
        uint32_t r1 = tf_bits(k1, k2, c0 + 1u);
        uint32_t r2 = tf_bits(k1, k2, c0 + 2u);
        uint32_t r3 = tf_bits(k1, k2, c0 + 3u);
        acc0 = fmaf(sbs, bits_to_scaled_normal(r0), acc0);
        acc1 = fmaf(sbs, bits_to_scaled_normal(r1), acc1);
        acc2 = fmaf(sbs, bits_to_scaled_normal(r2), acc2);
        acc3 = fmaf(sbs, bits_to_scaled_normal(r3), acc3);
    }

    const float4 xv = reinterpret_cast<const float4*>(x)[gid];
    float4 ov;
    ov.x = xv.x + acc0;
    ov.y = xv.y + acc1;
    ov.z = xv.z + acc2;
    ov.w = xv.w + acc3;
    reinterpret_cast<float4*>(out)[gid] = ov;
}

extern "C" void kernel_launch(void* const* d_in, const int* in_sizes, int n_in,
                              void* d_out, int out_size, void* d_ws, size_t ws_size,
                              hipStream_t stream) {
    const float* x = (const float*)d_in[0];
    const float* betas = (const float*)d_in[1];
    float* out = (float*)d_out;
    const int n = in_sizes[0];       // 64*3*256*256 = 12,582,912 (divisible by 4)
    const int n4 = n / 4;

    // jax.random.key(1) -> key data (0, 1).
    // split (partitionable / foldlike): keys[s] = threefry2x32((0,1), (0, s)).
    KeyArr keys;
    for (int s = 0; s < NSTEPS; ++s) {
        uint32_t o0, o1;
        threefry2x32_host(0u, 1u, 0u, (uint32_t)s, o0, o1);
        keys.k1[s] = o0;
        keys.k2[s] = o1;
    }
    keys.k1[NSTEPS] = 0u;   // prefetch pad
    keys.k2[NSTEPS] = 0u;

    const int blocks = (n4 + 255) / 256;
    hipLaunchKernelGGL(DiffusionProcess_21698174780217_kernel,
                       dim3(blocks), dim3(256), 0, stream,
                       x, betas, out, keys, n4);
}